// Round 1
// baseline (485.793 us; speedup 1.0000x reference)
//
#include <hip/hip_runtime.h>
#include <cstdint>
#include <cstddef>

#define D 128
#define NEG_SLOPE 0.2f
#define BN_EPS 1e-5f

// ---------- helpers ----------
static __device__ __forceinline__ unsigned short f2bf(float f) {
    uint32_t u = __float_as_uint(f);
    uint32_t r = (u + 0x7fffu + ((u >> 16) & 1u)) >> 16;
    return (unsigned short)r;
}

// ---------- zero ----------
__global__ void zero_kernel(int* a, int na, float* f, int nf) {
    int i = blockIdx.x * 256 + threadIdx.x;
    if (i < na) a[i] = 0;
    if (i < nf) f[i] = 0.f;
}

// ---------- CSR build ----------
__global__ void hist_kernel(const int* __restrict__ dst, int* __restrict__ cnt, int E) {
    int e = blockIdx.x * 256 + threadIdx.x;
    if (e < E) atomicAdd(&cnt[dst[e]], 1);
}

__global__ void scan_block(const int* __restrict__ cnt, int* __restrict__ row_start,
                           int* __restrict__ bsum, int n) {
    __shared__ int tmp[256];
    int tid = threadIdx.x;
    int i = blockIdx.x * 256 + tid;
    int v = (i < n) ? cnt[i] : 0;
    tmp[tid] = v; __syncthreads();
    for (int off = 1; off < 256; off <<= 1) {
        int t = (tid >= off) ? tmp[tid - off] : 0;
        __syncthreads();
        tmp[tid] += t; __syncthreads();
    }
    if (i < n) row_start[i + 1] = tmp[tid];     // inclusive within block
    if (tid == 255) bsum[blockIdx.x] = tmp[255];
}

__global__ void scan_bsum(int* bsum, int nb) {
    __shared__ int tmp[256];
    int tid = threadIdx.x;
    int v = (tid < nb) ? bsum[tid] : 0;
    tmp[tid] = v; __syncthreads();
    for (int off = 1; off < 256; off <<= 1) {
        int t = (tid >= off) ? tmp[tid - off] : 0;
        __syncthreads();
        tmp[tid] += t; __syncthreads();
    }
    if (tid < nb) bsum[tid] = tmp[tid];
}

__global__ void scan_fix(int* __restrict__ row_start, const int* __restrict__ bsum, int n) {
    int i = blockIdx.x * 256 + threadIdx.x;
    if (i < n) {
        int add = (blockIdx.x > 0) ? bsum[blockIdx.x - 1] : 0;
        row_start[i + 1] += add;
    }
    if (i == 0) row_start[0] = 0;
}

__global__ void cursor_init(const int* __restrict__ row_start, int* __restrict__ cursor, int n) {
    int i = blockIdx.x * 256 + threadIdx.x;
    if (i < n) cursor[i] = row_start[i];
}

__global__ void scatter_kernel(const int* __restrict__ src, const int* __restrict__ dst,
                               int* __restrict__ cursor, int* __restrict__ esrc, int E) {
    int e = blockIdx.x * 256 + threadIdx.x;
    if (e < E) {
        int p = atomicAdd(&cursor[dst[e]], 1);
        esrc[p] = src[e];
    }
}

// ---------- dual GEMM: [n x 128] @ ([128x128]|[128x128]) -> xl (bf16), xr (f32) ----------
// Optional fused input transform: z = relu(X*scale[ch] + shift[ch])  (BN+ReLU of layer-1 output)
template<bool BN>
__global__ __launch_bounds__(256) void gemm_dual(
    const float* __restrict__ X, const float* __restrict__ Wl, const float* __restrict__ Wr,
    const float* __restrict__ scale, const float* __restrict__ shift,
    unsigned short* __restrict__ xl, float* __restrict__ xr, int n)
{
    __shared__ float lds[64 * 132];
    int t = threadIdx.x;
    int r0 = blockIdx.x * 64;
    // stage 64x128 X tile (apply BN+relu if BN)
    #pragma unroll
    for (int i = 0; i < 8; ++i) {
        int f = t + 256 * i;         // 0..2047 float4 groups
        int row = f >> 5;
        int c4 = f & 31;
        int gr = r0 + row;
        float4 v;
        if (gr < n) v = *(const float4*)(X + (size_t)gr * D + c4 * 4);
        else        v = make_float4(0.f, 0.f, 0.f, 0.f);
        if (BN) {
            int c = c4 * 4;
            v.x = fmaxf(v.x * scale[c + 0] + shift[c + 0], 0.f);
            v.y = fmaxf(v.y * scale[c + 1] + shift[c + 1], 0.f);
            v.z = fmaxf(v.z * scale[c + 2] + shift[c + 2], 0.f);
            v.w = fmaxf(v.w * scale[c + 3] + shift[c + 3], 0.f);
        }
        *(float4*)&lds[row * 132 + c4 * 4] = v;
    }
    __syncthreads();

    int tx = t & 31, ty = t >> 5;                 // tx: col group, ty: row group
    const float* Wsel = (tx < 16) ? Wl : Wr;
    int j0 = (tx & 15) * 8;
    float acc[8][8];
    #pragma unroll
    for (int a = 0; a < 8; ++a)
        #pragma unroll
        for (int b = 0; b < 8; ++b) acc[a][b] = 0.f;

    for (int k4 = 0; k4 < 32; ++k4) {
        int k = k4 * 4;
        float wv[4][8];
        #pragma unroll
        for (int kk = 0; kk < 4; ++kk) {
            float4 a = *(const float4*)(Wsel + (size_t)(k + kk) * D + j0);
            float4 b = *(const float4*)(Wsel + (size_t)(k + kk) * D + j0 + 4);
            wv[kk][0] = a.x; wv[kk][1] = a.y; wv[kk][2] = a.z; wv[kk][3] = a.w;
            wv[kk][4] = b.x; wv[kk][5] = b.y; wv[kk][6] = b.z; wv[kk][7] = b.w;
        }
        #pragma unroll
        for (int rr = 0; rr < 8; ++rr) {
            float4 xv = *(const float4*)&lds[(ty * 8 + rr) * 132 + k];
            #pragma unroll
            for (int jc = 0; jc < 8; ++jc) {
                acc[rr][jc] += xv.x * wv[0][jc];
                acc[rr][jc] += xv.y * wv[1][jc];
                acc[rr][jc] += xv.z * wv[2][jc];
                acc[rr][jc] += xv.w * wv[3][jc];
            }
        }
    }

    #pragma unroll
    for (int rr = 0; rr < 8; ++rr) {
        int gr = r0 + ty * 8 + rr;
        if (gr >= n) continue;
        if (tx < 16) {
            #pragma unroll
            for (int jc = 0; jc < 8; ++jc)
                xl[(size_t)gr * D + j0 + jc] = f2bf(acc[rr][jc]);
        } else {
            #pragma unroll
            for (int jc = 0; jc < 8; ++jc)
                xr[(size_t)gr * D + j0 + jc] = acc[rr][jc];
        }
    }
}

// ---------- node-centric GATv2 with online softmax; one wave per node ----------
__global__ __launch_bounds__(256) void gat_kernel(
    const unsigned short* __restrict__ xl, const float* __restrict__ xr,
    const float* __restrict__ att, const float* __restrict__ bias,
    const int* __restrict__ row_start, const int* __restrict__ esrc,
    float* __restrict__ h, int n)
{
    int wid = threadIdx.x >> 6;
    int lane = threadIdx.x & 63;
    int v = blockIdx.x * 4 + wid;
    if (v >= n) return;

    int c0 = lane * 2;
    float a0 = att[c0], a1 = att[c0 + 1];
    float xr0 = xr[(size_t)v * D + c0];
    float xr1 = xr[(size_t)v * D + c0 + 1];

    float m = -3.0e38f, den = 0.f, acc0 = 0.f, acc1 = 0.f;
    int p = row_start[v], pe = row_start[v + 1];

    for (int i = p - 1; i < pe; ++i) {          // i==p-1 is the implicit self-loop
        int u = (i < p) ? v : esrc[i];
        uint32_t w = *(const uint32_t*)(xl + (size_t)u * D + c0);
        float x0 = __uint_as_float(w << 16);
        float x1 = __uint_as_float(w & 0xffff0000u);
        float e0 = x0 + xr0; e0 = (e0 > 0.f) ? e0 : NEG_SLOPE * e0;
        float e1 = x1 + xr1; e1 = (e1 > 0.f) ? e1 : NEG_SLOPE * e1;
        float partial = a0 * e0 + a1 * e1;
        partial += __shfl_xor(partial, 1);
        partial += __shfl_xor(partial, 2);
        partial += __shfl_xor(partial, 4);
        partial += __shfl_xor(partial, 8);      // 16-lane group = one head
        float logit = partial;
        float nm = fmaxf(m, logit);
        float sc = __expf(m - nm);
        float pex = __expf(logit - nm);
        den  = den  * sc + pex;
        acc0 = acc0 * sc + pex * x0;
        acc1 = acc1 * sc + pex * x1;
        m = nm;
    }
    float inv = 1.0f / den;
    h[(size_t)v * D + c0]     = acc0 * inv + bias[c0];
    h[(size_t)v * D + c0 + 1] = acc1 * inv + bias[c0 + 1];
}

// ---------- BN stats ----------
__global__ __launch_bounds__(256) void bn_stats(const float* __restrict__ h,
                                                float* __restrict__ gsum, float* __restrict__ gsum2, int n)
{
    int ch = threadIdx.x & 127;
    int half = threadIdx.x >> 7;
    float s = 0.f, s2 = 0.f;
    for (int r = blockIdx.x * 2 + half; r < n; r += gridDim.x * 2) {
        float v = h[(size_t)r * D + ch];
        s += v; s2 += v * v;
    }
    __shared__ float sm[256];
    sm[threadIdx.x] = s; __syncthreads();
    if (half == 0) { s += sm[threadIdx.x + 128]; atomicAdd(&gsum[ch], s); }
    __syncthreads();
    sm[threadIdx.x] = s2; __syncthreads();
    if (half == 0) { s2 += sm[threadIdx.x + 128]; atomicAdd(&gsum2[ch], s2); }
}

__global__ void bn_final(const float* __restrict__ gsum, const float* __restrict__ gsum2,
                         const float* __restrict__ gamma, const float* __restrict__ beta,
                         float* __restrict__ scale, float* __restrict__ shift, float inv_n)
{
    int c = threadIdx.x;     // 128 threads
    float mu = gsum[c] * inv_n;
    float var = gsum2[c] * inv_n - mu * mu;
    float inv = rsqrtf(var + BN_EPS);
    float sc = gamma[c] * inv;
    scale[c] = sc;
    shift[c] = beta[c] - mu * sc;
}

// ---------- final: out = relu(bn2(h2) + x) ----------
__global__ __launch_bounds__(256) void final_kernel(
    const float* __restrict__ h2, const float* __restrict__ x,
    const float* __restrict__ scale, const float* __restrict__ shift,
    float* __restrict__ out, int total)
{
    int i = blockIdx.x * 256 + threadIdx.x;
    if (i * 4 >= total) return;
    float4 hv = ((const float4*)h2)[i];
    float4 xv = ((const float4*)x)[i];
    int c = (i * 4) & 127;
    float4 o;
    o.x = fmaxf(hv.x * scale[c + 0] + shift[c + 0] + xv.x, 0.f);
    o.y = fmaxf(hv.y * scale[c + 1] + shift[c + 1] + xv.y, 0.f);
    o.z = fmaxf(hv.z * scale[c + 2] + shift[c + 2] + xv.z, 0.f);
    o.w = fmaxf(hv.w * scale[c + 3] + shift[c + 3] + xv.w, 0.f);
    ((float4*)out)[i] = o;
}

// ---------- launch ----------
extern "C" void kernel_launch(void* const* d_in, const int* in_sizes, int n_in,
                              void* d_out, int out_size, void* d_ws, size_t ws_size,
                              hipStream_t stream)
{
    const float* x    = (const float*)d_in[0];
    const int*   ei   = (const int*)  d_in[1];
    const float* Wl1  = (const float*)d_in[2];
    const float* Wr1  = (const float*)d_in[3];
    const float* att1 = (const float*)d_in[4];
    const float* b1   = (const float*)d_in[5];
    const float* g1   = (const float*)d_in[6];
    const float* be1  = (const float*)d_in[7];
    const float* Wl2  = (const float*)d_in[8];
    const float* Wr2  = (const float*)d_in[9];
    const float* att2 = (const float*)d_in[10];
    const float* b2   = (const float*)d_in[11];
    const float* g2   = (const float*)d_in[12];
    const float* be2  = (const float*)d_in[13];
    float* out = (float*)d_out;

    int n = in_sizes[0] / D;
    int E = in_sizes[1] / 2;
    const int* e_src = ei;
    const int* e_dst = ei + E;

    char* w = (char*)d_ws;
    auto alloc = [&](size_t bytes) -> char* {
        char* p = w;
        w += (bytes + 255) / 256 * 256;
        return p;
    };
    unsigned short* xl = (unsigned short*)alloc((size_t)n * D * 2);
    float* xr          = (float*)alloc((size_t)n * D * 4);
    float* h           = (float*)alloc((size_t)n * D * 4);
    int* row_start     = (int*)alloc((size_t)(n + 1) * 4);
    int* cnt           = (int*)alloc((size_t)n * 4);
    int* cursor        = (int*)alloc((size_t)n * 4);
    int* esrc          = (int*)alloc((size_t)E * 4);
    int* bsum          = (int*)alloc(256 * 4);
    float* bn          = (float*)alloc(8 * 128 * 4);
    // bn layout: [0]=sum1 [128]=sq1 [256]=scale1 [384]=shift1 [512]=sum2 [640]=sq2 [768]=scale2 [896]=shift2

    int nb = (n + 255) / 256;

    zero_kernel<<<(n + 255) / 256, 256, 0, stream>>>(cnt, n, bn, 1024);
    hist_kernel<<<(E + 255) / 256, 256, 0, stream>>>(e_dst, cnt, E);
    scan_block<<<nb, 256, 0, stream>>>(cnt, row_start, bsum, n);
    scan_bsum<<<1, 256, 0, stream>>>(bsum, nb);
    scan_fix<<<nb, 256, 0, stream>>>(row_start, bsum, n);
    cursor_init<<<(n + 255) / 256, 256, 0, stream>>>(row_start, cursor, n);
    scatter_kernel<<<(E + 255) / 256, 256, 0, stream>>>(e_src, e_dst, cursor, esrc, E);

    // layer 1
    gemm_dual<false><<<(n + 63) / 64, 256, 0, stream>>>(x, Wl1, Wr1, nullptr, nullptr, xl, xr, n);
    gat_kernel<<<(n + 3) / 4, 256, 0, stream>>>(xl, xr, att1, b1, row_start, esrc, h, n);
    bn_stats<<<256, 256, 0, stream>>>(h, bn + 0, bn + 128, n);
    bn_final<<<1, 128, 0, stream>>>(bn + 0, bn + 128, g1, be1, bn + 256, bn + 384, 1.0f / n);

    // layer 2 (BN1+ReLU fused into GEMM input read)
    gemm_dual<true><<<(n + 63) / 64, 256, 0, stream>>>(h, Wl2, Wr2, bn + 256, bn + 384, xl, xr, n);
    gat_kernel<<<(n + 3) / 4, 256, 0, stream>>>(xl, xr, att2, b2, row_start, esrc, h, n);
    bn_stats<<<256, 256, 0, stream>>>(h, bn + 512, bn + 640, n);
    bn_final<<<1, 128, 0, stream>>>(bn + 512, bn + 640, g2, be2, bn + 768, bn + 896, 1.0f / n);

    final_kernel<<<((n * D / 4) + 255) / 256, 256, 0, stream>>>(h, x, bn + 768, bn + 896, out, n * D);
}

// Round 2
// 377.491 us; speedup vs baseline: 1.2869x; 1.2869x over previous
//
#include <hip/hip_runtime.h>
#include <cstdint>
#include <cstddef>

#define D 128
#define NEG_SLOPE 0.2f
#define BN_EPS 1e-5f

typedef __attribute__((ext_vector_type(8))) short bf16x8;
typedef __attribute__((ext_vector_type(4))) float f32x4;

// ---------- helpers ----------
static __device__ __forceinline__ unsigned short f2bf(float f) {
    uint32_t u = __float_as_uint(f);
    uint32_t r = (u + 0x7fffu + ((u >> 16) & 1u)) >> 16;
    return (unsigned short)r;
}

// ---------- zero ----------
__global__ void zero_kernel(int* a, int na, float* f, int nf) {
    int i = blockIdx.x * 256 + threadIdx.x;
    if (i < na) a[i] = 0;
    if (i < nf) f[i] = 0.f;
}

// ---------- CSR build ----------
__global__ void hist_kernel(const int* __restrict__ dst, int* __restrict__ cnt, int E) {
    int e = blockIdx.x * 256 + threadIdx.x;
    if (e < E) atomicAdd(&cnt[dst[e]], 1);
}

__global__ void scan_block(const int* __restrict__ cnt, int* __restrict__ row_start,
                           int* __restrict__ bsum, int n) {
    __shared__ int tmp[256];
    int tid = threadIdx.x;
    int i = blockIdx.x * 256 + tid;
    int v = (i < n) ? cnt[i] : 0;
    tmp[tid] = v; __syncthreads();
    for (int off = 1; off < 256; off <<= 1) {
        int t = (tid >= off) ? tmp[tid - off] : 0;
        __syncthreads();
        tmp[tid] += t; __syncthreads();
    }
    if (i < n) row_start[i + 1] = tmp[tid];
    if (tid == 255) bsum[blockIdx.x] = tmp[255];
}

__global__ void scan_bsum(int* bsum, int nb) {
    __shared__ int tmp[256];
    int tid = threadIdx.x;
    int v = (tid < nb) ? bsum[tid] : 0;
    tmp[tid] = v; __syncthreads();
    for (int off = 1; off < 256; off <<= 1) {
        int t = (tid >= off) ? tmp[tid - off] : 0;
        __syncthreads();
        tmp[tid] += t; __syncthreads();
    }
    if (tid < nb) bsum[tid] = tmp[tid];
}

__global__ void scan_fix(int* __restrict__ row_start, const int* __restrict__ bsum, int n) {
    int i = blockIdx.x * 256 + threadIdx.x;
    if (i < n) {
        int add = (blockIdx.x > 0) ? bsum[blockIdx.x - 1] : 0;
        row_start[i + 1] += add;
    }
    if (i == 0) row_start[0] = 0;
}

__global__ void cursor_init(const int* __restrict__ row_start, int* __restrict__ cursor, int n) {
    int i = blockIdx.x * 256 + threadIdx.x;
    if (i < n) cursor[i] = row_start[i];
}

__global__ void scatter_kernel(const int* __restrict__ src, const int* __restrict__ dst,
                               int* __restrict__ cursor, int* __restrict__ esrc, int E) {
    int e = blockIdx.x * 256 + threadIdx.x;
    if (e < E) {
        int p = atomicAdd(&cursor[dst[e]], 1);
        esrc[p] = src[e];
    }
}

// ---------- weight repack into MFMA B-fragment order ----------
// Combined B[128][256] = [Wl | Wr]. Fragment value at flat index
// ((jt*4 + kt)*64 + lane)*8 + i  is  B[kt*32 + (lane>>4)*8 + i][jt*16 + (lane&15)].
// Any k-bijection shared between A and B fragments is exact (A/B layouts mirrored).
__global__ void repack_w(const float* __restrict__ Wl, const float* __restrict__ Wr,
                         unsigned short* __restrict__ Bp) {
    int idx = blockIdx.x * 256 + threadIdx.x;   // 0..32767
    int i    = idx & 7;
    int lane = (idx >> 3) & 63;
    int kt   = (idx >> 9) & 3;
    int jt   = idx >> 11;                        // 0..15
    int k   = kt * 32 + (lane >> 4) * 8 + i;
    int col = jt * 16 + (lane & 15);
    float v = (col < 128) ? Wl[k * 128 + col] : Wr[k * 128 + (col - 128)];
    Bp[idx] = f2bf(v);
}

// ---------- MFMA dual GEMM: [n x 128] @ [128 x 256] -> xl (bf16), xr (f32) ----------
// One wave computes 16 rows x 256 cols. Optional fused A transform relu(x*scale+shift).
template<bool BN>
__global__ __launch_bounds__(256) void gemm_mfma(
    const float* __restrict__ X, const unsigned short* __restrict__ Bp,
    const float* __restrict__ scale, const float* __restrict__ shift,
    unsigned short* __restrict__ xl, float* __restrict__ xr, int n)
{
    int wid = threadIdx.x >> 6, lane = threadIdx.x & 63;
    int nw = (n + 15) >> 4;
    int wrow = blockIdx.x * 4 + wid;
    if (wrow >= nw) return;
    int r0 = wrow * 16;
    int m = lane & 15, hi = lane >> 4;

    f32x4 acc[16];
    #pragma unroll
    for (int jt = 0; jt < 16; ++jt) acc[jt] = (f32x4){0.f, 0.f, 0.f, 0.f};

    int rld = r0 + m; if (rld > n - 1) rld = n - 1;
    const float* xrow = X + (size_t)rld * D;

    #pragma unroll
    for (int kt = 0; kt < 4; ++kt) {
        int kb = kt * 32 + hi * 8;
        float4 av4 = *(const float4*)(xrow + kb);
        float4 bv4 = *(const float4*)(xrow + kb + 4);
        float av[8] = {av4.x, av4.y, av4.z, av4.w, bv4.x, bv4.y, bv4.z, bv4.w};
        if (BN) {
            #pragma unroll
            for (int i = 0; i < 8; ++i)
                av[i] = fmaxf(av[i] * scale[kb + i] + shift[kb + i], 0.f);
        }
        bf16x8 afrag;
        #pragma unroll
        for (int i = 0; i < 8; ++i) afrag[i] = (short)f2bf(av[i]);
        #pragma unroll
        for (int jt = 0; jt < 16; ++jt) {
            bf16x8 bfrag = *(const bf16x8*)(Bp + (size_t)((jt * 4 + kt) * 64 + lane) * 8);
            acc[jt] = __builtin_amdgcn_mfma_f32_16x16x32_bf16(afrag, bfrag, acc[jt], 0, 0, 0);
        }
    }

    // C/D layout (m89): col = lane&15, row = (lane>>4)*4 + reg
    #pragma unroll
    for (int jt = 0; jt < 16; ++jt) {
        #pragma unroll
        for (int r = 0; r < 4; ++r) {
            int row = r0 + hi * 4 + r;
            if (row >= n) continue;
            int col = jt * 16 + m;
            float v = acc[jt][r];
            if (jt < 8) xl[(size_t)row * D + col] = f2bf(v);
            else        xr[(size_t)row * D + (col - 128)] = v;
        }
    }
}

// ---------- node-centric GATv2, online softmax with defer-max, 4-edge chunks ----------
__global__ __launch_bounds__(256) void gat_kernel(
    const unsigned short* __restrict__ xl, const float* __restrict__ xr,
    const float* __restrict__ att, const float* __restrict__ bias,
    const int* __restrict__ row_start, const int* __restrict__ esrc,
    float* __restrict__ h, int n)
{
    int wid = threadIdx.x >> 6;
    int lane = threadIdx.x & 63;
    int v = blockIdx.x * 4 + wid;
    if (v >= n) return;

    int c0 = lane * 2;
    float a0 = att[c0], a1 = att[c0 + 1];
    float xr0 = xr[(size_t)v * D + c0];
    float xr1 = xr[(size_t)v * D + c0 + 1];

    // self-loop first: initializes running max
    uint32_t ws = *(const uint32_t*)(xl + (size_t)v * D + c0);
    float sx0 = __uint_as_float(ws << 16);
    float sx1 = __uint_as_float(ws & 0xffff0000u);
    float e0 = sx0 + xr0; e0 = (e0 > 0.f) ? e0 : NEG_SLOPE * e0;
    float e1 = sx1 + xr1; e1 = (e1 > 0.f) ? e1 : NEG_SLOPE * e1;
    float part = a0 * e0 + a1 * e1;
    part += __shfl_xor(part, 1);
    part += __shfl_xor(part, 2);
    part += __shfl_xor(part, 4);
    part += __shfl_xor(part, 8);            // 16-lane group = one head
    float m = part;
    float den = 1.f, acc0 = sx0, acc1 = sx1;

    int p = row_start[v], pe = row_start[v + 1];
    for (int i = p; i < pe; i += 4) {
        int u[4]; uint32_t w[4];
        u[0] = esrc[i];
        u[1] = (i + 1 < pe) ? esrc[i + 1] : u[0];
        u[2] = (i + 2 < pe) ? esrc[i + 2] : u[0];
        u[3] = (i + 3 < pe) ? esrc[i + 3] : u[0];
        #pragma unroll
        for (int j = 0; j < 4; ++j)
            w[j] = *(const uint32_t*)(xl + (size_t)u[j] * D + c0);

        float lg[4], x0v[4], x1v[4];
        #pragma unroll
        for (int j = 0; j < 4; ++j) {
            float x0 = __uint_as_float(w[j] << 16);
            float x1 = __uint_as_float(w[j] & 0xffff0000u);
            x0v[j] = x0; x1v[j] = x1;
            float f0 = x0 + xr0; f0 = (f0 > 0.f) ? f0 : NEG_SLOPE * f0;
            float f1 = x1 + xr1; f1 = (f1 > 0.f) ? f1 : NEG_SLOPE * f1;
            float pt = a0 * f0 + a1 * f1;
            pt += __shfl_xor(pt, 1);
            pt += __shfl_xor(pt, 2);
            pt += __shfl_xor(pt, 4);
            pt += __shfl_xor(pt, 8);
            lg[j] = pt;
        }
        #pragma unroll
        for (int j = 0; j < 4; ++j) {
            if (i + j < pe) {               // wave-uniform predicate
                if (__any(lg[j] > m + 8.f)) {
                    float nm = fmaxf(m, lg[j]);
                    float sc = __expf(m - nm);
                    den *= sc; acc0 *= sc; acc1 *= sc; m = nm;
                }
                float pex = __expf(lg[j] - m);
                den += pex; acc0 += pex * x0v[j]; acc1 += pex * x1v[j];
            }
        }
    }
    float inv = 1.0f / den;
    h[(size_t)v * D + c0]     = acc0 * inv + bias[c0];
    h[(size_t)v * D + c0 + 1] = acc1 * inv + bias[c0 + 1];
}

// ---------- BN stats ----------
__global__ __launch_bounds__(256) void bn_stats(const float* __restrict__ h,
                                                float* __restrict__ gsum, float* __restrict__ gsum2, int n)
{
    int ch = threadIdx.x & 127;
    int half = threadIdx.x >> 7;
    float s = 0.f, s2 = 0.f;
    for (int r = blockIdx.x * 2 + half; r < n; r += gridDim.x * 2) {
        float v = h[(size_t)r * D + ch];
        s += v; s2 += v * v;
    }
    __shared__ float sm[256];
    sm[threadIdx.x] = s; __syncthreads();
    if (half == 0) { s += sm[threadIdx.x + 128]; atomicAdd(&gsum[ch], s); }
    __syncthreads();
    sm[threadIdx.x] = s2; __syncthreads();
    if (half == 0) { s2 += sm[threadIdx.x + 128]; atomicAdd(&gsum2[ch], s2); }
}

__global__ void bn_final(const float* __restrict__ gsum, const float* __restrict__ gsum2,
                         const float* __restrict__ gamma, const float* __restrict__ beta,
                         float* __restrict__ scale, float* __restrict__ shift, float inv_n)
{
    int c = threadIdx.x;     // 128 threads
    float mu = gsum[c] * inv_n;
    float var = gsum2[c] * inv_n - mu * mu;
    float inv = rsqrtf(var + BN_EPS);
    float sc = gamma[c] * inv;
    scale[c] = sc;
    shift[c] = beta[c] - mu * sc;
}

// ---------- final: out = relu(bn2(h2) + x) ----------
__global__ __launch_bounds__(256) void final_kernel(
    const float* __restrict__ h2, const float* __restrict__ x,
    const float* __restrict__ scale, const float* __restrict__ shift,
    float* __restrict__ out, int total)
{
    int i = blockIdx.x * 256 + threadIdx.x;
    if (i * 4 >= total) return;
    float4 hv = ((const float4*)h2)[i];
    float4 xv = ((const float4*)x)[i];
    int c = (i * 4) & 127;
    float4 o;
    o.x = fmaxf(hv.x * scale[c + 0] + shift[c + 0] + xv.x, 0.f);
    o.y = fmaxf(hv.y * scale[c + 1] + shift[c + 1] + xv.y, 0.f);
    o.z = fmaxf(hv.z * scale[c + 2] + shift[c + 2] + xv.z, 0.f);
    o.w = fmaxf(hv.w * scale[c + 3] + shift[c + 3] + xv.w, 0.f);
    ((float4*)out)[i] = o;
}

// ---------- launch ----------
extern "C" void kernel_launch(void* const* d_in, const int* in_sizes, int n_in,
                              void* d_out, int out_size, void* d_ws, size_t ws_size,
                              hipStream_t stream)
{
    const float* x    = (const float*)d_in[0];
    const int*   ei   = (const int*)  d_in[1];
    const float* Wl1  = (const float*)d_in[2];
    const float* Wr1  = (const float*)d_in[3];
    const float* att1 = (const float*)d_in[4];
    const float* b1   = (const float*)d_in[5];
    const float* g1   = (const float*)d_in[6];
    const float* be1  = (const float*)d_in[7];
    const float* Wl2  = (const float*)d_in[8];
    const float* Wr2  = (const float*)d_in[9];
    const float* att2 = (const float*)d_in[10];
    const float* b2   = (const float*)d_in[11];
    const float* g2   = (const float*)d_in[12];
    const float* be2  = (const float*)d_in[13];
    float* out = (float*)d_out;

    int n = in_sizes[0] / D;
    int E = in_sizes[1] / 2;
    const int* e_src = ei;
    const int* e_dst = ei + E;

    char* w = (char*)d_ws;
    auto alloc = [&](size_t bytes) -> char* {
        char* p = w;
        w += (bytes + 255) / 256 * 256;
        return p;
    };
    unsigned short* xl = (unsigned short*)alloc((size_t)n * D * 2);
    float* xr          = (float*)alloc((size_t)n * D * 4);
    float* h           = (float*)alloc((size_t)n * D * 4);
    int* row_start     = (int*)alloc((size_t)(n + 1) * 4);
    int* cnt           = (int*)alloc((size_t)n * 4);
    int* cursor        = (int*)alloc((size_t)n * 4);
    int* esrc          = (int*)alloc((size_t)E * 4);
    int* bsum          = (int*)alloc(256 * 4);
    float* bn          = (float*)alloc(8 * 128 * 4);
    unsigned short* Bp1 = (unsigned short*)alloc(32768 * 2);
    unsigned short* Bp2 = (unsigned short*)alloc(32768 * 2);
    // bn layout: [0]=sum1 [128]=sq1 [256]=scale1 [384]=shift1 [512]=sum2 [640]=sq2 [768]=scale2 [896]=shift2

    int nb = (n + 255) / 256;
    int gemm_blocks = (((n + 15) / 16) + 3) / 4;

    zero_kernel<<<(n + 255) / 256, 256, 0, stream>>>(cnt, n, bn, 1024);
    hist_kernel<<<(E + 255) / 256, 256, 0, stream>>>(e_dst, cnt, E);
    scan_block<<<nb, 256, 0, stream>>>(cnt, row_start, bsum, n);
    scan_bsum<<<1, 256, 0, stream>>>(bsum, nb);
    scan_fix<<<nb, 256, 0, stream>>>(row_start, bsum, n);
    cursor_init<<<(n + 255) / 256, 256, 0, stream>>>(row_start, cursor, n);
    scatter_kernel<<<(E + 255) / 256, 256, 0, stream>>>(e_src, e_dst, cursor, esrc, E);
    repack_w<<<128, 256, 0, stream>>>(Wl1, Wr1, Bp1);
    repack_w<<<128, 256, 0, stream>>>(Wl2, Wr2, Bp2);

    // layer 1
    gemm_mfma<false><<<gemm_blocks, 256, 0, stream>>>(x, Bp1, nullptr, nullptr, xl, xr, n);
    gat_kernel<<<(n + 3) / 4, 256, 0, stream>>>(xl, xr, att1, b1, row_start, esrc, h, n);
    bn_stats<<<256, 256, 0, stream>>>(h, bn + 0, bn + 128, n);
    bn_final<<<1, 128, 0, stream>>>(bn + 0, bn + 128, g1, be1, bn + 256, bn + 384, 1.0f / n);

    // layer 2 (BN1+ReLU fused into GEMM A-load)
    gemm_mfma<true><<<gemm_blocks, 256, 0, stream>>>(h, Bp2, bn + 256, bn + 384, xl, xr, n);
    gat_kernel<<<(n + 3) / 4, 256, 0, stream>>>(xl, xr, att2, b2, row_start, esrc, h, n);
    bn_stats<<<256, 256, 0, stream>>>(h, bn + 512, bn + 640, n);
    bn_final<<<1, 128, 0, stream>>>(bn + 512, bn + 640, g2, be2, bn + 768, bn + 896, 1.0f / n);

    final_kernel<<<((n * D / 4) + 255) / 256, 256, 0, stream>>>(h, x, bn + 768, bn + 896, out, n * D);
}